// Round 1
// baseline (762.809 us; speedup 1.0000x reference)
//
#include <hip/hip_runtime.h>
#include <stdint.h>

// Problem constants (match reference)
#define KH 8
#define HD 128
#define GD 64
#define UD 128
#define WPAD 136   // 128 + 8 bf16 pad: row stride 68 words -> bank-balanced ds_read_b128
#define NPB 128    // nodes per block (8 waves x 16)

typedef __attribute__((ext_vector_type(8))) short short8;   // 8 x bf16 (MFMA A/B frag)
typedef __attribute__((ext_vector_type(4))) float f32x4;    // MFMA C/D frag

__device__ __forceinline__ unsigned short f2bf(float x) {
    union { float f; unsigned u; } v; v.f = x;
    return (unsigned short)((v.u + 0x7fffu + ((v.u >> 16) & 1u)) >> 16);  // RNE
}

__device__ __forceinline__ short8 pack8(const float4 a, const float4 b) {
    short8 r;
    r[0] = (short)f2bf(a.x); r[1] = (short)f2bf(a.y);
    r[2] = (short)f2bf(a.z); r[3] = (short)f2bf(a.w);
    r[4] = (short)f2bf(b.x); r[5] = (short)f2bf(b.y);
    r[6] = (short)f2bf(b.z); r[7] = (short)f2bf(b.w);
    return r;
}

// ---------------- pre-kernel: bf16-convert + transpose weights into padded images ------
// ws layout (bf16 elements):
//   [0)                : WghT [k][g][WPAD]  = Wgh[k][h][g]     (8*64*136)
//   [KH*GD*WPAD)       : WuhT [k][u][WPAD]  = Wuh[k][h][u]     (8*128*136)
//   [... + KH*UD*WPAD) : WgvT [g][WPAD]     = Wgv[h][g]        (64*136)
__global__ void prep_weights(const float* __restrict__ Wgv,
                             const float* __restrict__ Wgh,
                             const float* __restrict__ Wuh,
                             unsigned short* __restrict__ ws) {
    const int wghN = KH * GD * WPAD;
    const int wuhN = KH * UD * WPAD;
    const int wgvN = GD * WPAD;
    int idx = blockIdx.x * 256 + threadIdx.x;
    if (idx >= wghN + wuhN + wgvN) return;
    float val = 0.f;
    if (idx < wghN) {
        int k = idx / (GD * WPAD), rem = idx % (GD * WPAD);
        int g = rem / WPAD, h = rem % WPAD;
        if (h < HD) val = Wgh[((size_t)k * HD + h) * GD + g];
    } else if (idx < wghN + wuhN) {
        int j = idx - wghN;
        int k = j / (UD * WPAD), rem = j % (UD * WPAD);
        int u = rem / WPAD, h = rem % WPAD;
        if (h < HD) val = Wuh[((size_t)k * HD + h) * UD + u];
    } else {
        int j = idx - wghN - wuhN;
        int g = j / WPAD, h = j % WPAD;
        if (h < HD) val = Wgv[(size_t)h * GD + g];
    }
    ws[idx] = f2bf(val);
}

// async copy of 1KB chunks global->LDS (dest layout == source layout, pad baked in)
__device__ __forceinline__ void cp_lds(const unsigned short* gs, unsigned short* ld,
                                       int nch, int wave, int lane) {
    for (int i = wave; i < nch; i += 8) {
        __builtin_amdgcn_global_load_lds(
            (const __attribute__((address_space(1))) unsigned int*)(gs + i * 512 + lane * 8),
            (__attribute__((address_space(3))) unsigned int*)(ld + i * 512),
            16, 0, 0);
    }
}

// ---------------- main kernel ----------------------------------------------------------
// Per block: 128 nodes, 8 waves, 16-node MFMA strip per wave.
// A-fragments (H rows, bf16) are built register-direct from global: lane (cc,q) loads
// H[node=base+wave*16+cc][kb*32+q*8 .. +7] — exactly the 16x16x32 A layout. No LDS H tile.
// Per k: ONE staging phase (WghT[k] 17KB + WuhT[k] 34KB via global_load_lds), 2 barriers.
__launch_bounds__(512, 4)
__global__ void ghatt_main(const float* __restrict__ vt, const float* __restrict__ H,
                           const unsigned short* __restrict__ ws,
                           float* __restrict__ out, int N) {
    __shared__ __attribute__((aligned(16))) unsigned short lds_w[(GD + UD) * WPAD]; // 52224 B -> 2 blocks/CU (VGPR-capped)

    const int tid  = threadIdx.x;
    const int wave = tid >> 6;
    const int lane = tid & 63;
    const int cc   = lane & 15;   // MFMA col / A-row index
    const int q    = lane >> 4;   // quad
    const int nodebase = blockIdx.x * NPB;
    const int anode = nodebase + wave * 16 + cc;   // this lane's A-fragment row
    const bool valid = anode < N;

    const unsigned short* wghT = ws;
    const unsigned short* wuhT = ws + (size_t)KH * GD * WPAD;
    const unsigned short* wgvT = wuhT + (size_t)KH * UD * WPAD;

    unsigned short* lds_wg = lds_w;                 // 64 rows  (WgvT in phase0, WghT[k] in loop)
    unsigned short* lds_wu = lds_w + GD * WPAD;     // 128 rows (WuhT[k], both halves)

    const float4 z4 = make_float4(0.f, 0.f, 0.f, 0.f);
    float4 hreg[8];   // prefetch regs: this lane's 32 floats of H in fragment order

    // ---- phase 0: stage WgvT; load vt fragment; compute g_key (stays in regs) ---------
    cp_lds(wgvT, lds_wg, 17, wave, lane);
    float4 vreg[8];
#pragma unroll
    for (int kb = 0; kb < 4; kb++)
#pragma unroll
        for (int j = 0; j < 2; j++)
            vreg[2 * kb + j] = valid ? ((const float4*)vt)[(size_t)anode * 32 + kb * 8 + q * 2 + j] : z4;
    __syncthreads();   // WgvT staged (drains vreg too)

    // issue H k=0 fragment loads early; consumed at k=0 pack
#pragma unroll
    for (int kb = 0; kb < 4; kb++)
#pragma unroll
        for (int j = 0; j < 2; j++)
            hreg[2 * kb + j] = valid ? ((const float4*)H)[(size_t)anode * 32 + kb * 8 + q * 2 + j] : z4;

    f32x4 gkeyv[4];   // g_key in C-layout: row(node)=4q+r, col(g)=cc+16t — same layout as gq
    {
        short8 vf[4];
#pragma unroll
        for (int kb = 0; kb < 4; kb++) vf[kb] = pack8(vreg[2 * kb], vreg[2 * kb + 1]);
#pragma unroll
        for (int t = 0; t < 4; t++) {
            f32x4 acc = {0.f, 0.f, 0.f, 0.f};
#pragma unroll
            for (int kb = 0; kb < 4; kb++) {
                short8 vb = *(const short8*)&lds_wg[(t * 16 + cc) * WPAD + kb * 32 + q * 8];
                acc = __builtin_amdgcn_mfma_f32_16x16x32_bf16(vf[kb], vb, acc, 0, 0, 0);
            }
            gkeyv[t] = acc;
        }
    }

    f32x4 Uacc[8];
#pragma unroll
    for (int t = 0; t < 8; t++) { Uacc[t].x = Uacc[t].y = Uacc[t].z = Uacc[t].w = 0.f; }
    float den[4] = {0.f, 0.f, 0.f, 0.f};

    // ---- k loop: single pass over H, 2 barriers per iteration --------------------------
    for (int k = 0; k < KH; k++) {
        __syncthreads();   // all waves done reading lds_w from previous phase
        cp_lds(wghT + (size_t)k * (GD * WPAD), lds_wg, 17, wave, lane);
        cp_lds(wuhT + (size_t)k * (UD * WPAD), lds_wu, 34, wave, lane);  // both u halves
        short8 va[4];      // pack H fragment (VALU) under the staging latency
#pragma unroll
        for (int kb = 0; kb < 4; kb++) va[kb] = pack8(hreg[2 * kb], hreg[2 * kb + 1]);
        __syncthreads();   // weights staged (vmcnt(0) drain)

        // g_query = H @ Wgh[k]  (C-layout, matches gkeyv)
        f32x4 gqv[4];
#pragma unroll
        for (int t = 0; t < 4; t++) {
            f32x4 acc = {0.f, 0.f, 0.f, 0.f};
#pragma unroll
            for (int kb = 0; kb < 4; kb++) {
                short8 vb = *(const short8*)&lds_wg[(t * 16 + cc) * WPAD + kb * 32 + q * 8];
                acc = __builtin_amdgcn_mfma_f32_16x16x32_bf16(va[kb], vb, acc, 0, 0, 0);
            }
            gqv[t] = acc;
        }

        // score: per-row dot over g, reduced across the 16 column-lanes of each quad
        float part[4];
#pragma unroll
        for (int r = 0; r < 4; r++)
            part[r] = gqv[0][r] * gkeyv[0][r] + gqv[1][r] * gkeyv[1][r]
                    + gqv[2][r] * gkeyv[2][r] + gqv[3][r] * gkeyv[3][r];
#pragma unroll
        for (int m2 = 1; m2 < 16; m2 <<= 1) {
#pragma unroll
            for (int r = 0; r < 4; r++) part[r] += __shfl_xor(part[r], m2);
        }
        float gg[4];
#pragma unroll
        for (int r = 0; r < 4; r++) {
            float x = part[r];
            x = (x >= 0.f) ? x : 0.01f * x;      // LeakyReLU(0.01)
            gg[r] = __expf(x * 0.125f);          // / sqrt(64)
            den[r] += gg[r];
        }

        // prefetch next H fragment (issued after gqv dies -> keeps peak VGPR <= 128;
        // overlaps the 32 PV MFMAs below, drains at next iteration's staging barrier)
        if (k < KH - 1) {
#pragma unroll
            for (int kb = 0; kb < 4; kb++)
#pragma unroll
                for (int j = 0; j < 2; j++)
                    hreg[2 * kb + j] = valid
                        ? ((const float4*)H)[((size_t)(k + 1) * N + anode) * 32 + kb * 8 + q * 2 + j] : z4;
        }

        // U += g * (H @ Wuh), u 0..63
#pragma unroll
        for (int t = 0; t < 4; t++) {
            f32x4 acc = {0.f, 0.f, 0.f, 0.f};
#pragma unroll
            for (int kb = 0; kb < 4; kb++) {
                short8 vb = *(const short8*)&lds_wu[(t * 16 + cc) * WPAD + kb * 32 + q * 8];
                acc = __builtin_amdgcn_mfma_f32_16x16x32_bf16(va[kb], vb, acc, 0, 0, 0);
            }
#pragma unroll
            for (int r = 0; r < 4; r++) Uacc[t][r] += gg[r] * acc[r];
        }
        // u 64..127
#pragma unroll
        for (int t = 0; t < 4; t++) {
            f32x4 acc = {0.f, 0.f, 0.f, 0.f};
#pragma unroll
            for (int kb = 0; kb < 4; kb++) {
                short8 vb = *(const short8*)&lds_wu[(64 + t * 16 + cc) * WPAD + kb * 32 + q * 8];
                acc = __builtin_amdgcn_mfma_f32_16x16x32_bf16(va[kb], vb, acc, 0, 0, 0);
            }
#pragma unroll
            for (int r = 0; r < 4; r++) Uacc[4 + t][r] += gg[r] * acc[r];
        }
    }

    // ---- epilogue: normalize, lrelu, store ---------------------------------------------
    float inv[4];
#pragma unroll
    for (int r = 0; r < 4; r++) inv[r] = 1.f / den[r];
#pragma unroll
    for (int t = 0; t < 8; t++) {
#pragma unroll
        for (int r = 0; r < 4; r++) {
            float u = Uacc[t][r] * inv[r];
            u = (u >= 0.f) ? u : 0.01f * u;
            int node = nodebase + wave * 16 + 4 * q + r;
            if (node < N) out[(size_t)node * UD + t * 16 + cc] = u;
        }
    }
}

extern "C" void kernel_launch(void* const* d_in, const int* in_sizes, int n_in,
                              void* d_out, int out_size, void* d_ws, size_t ws_size,
                              hipStream_t stream) {
    const float* vt  = (const float*)d_in[0];
    const float* H   = (const float*)d_in[1];
    const float* Wgv = (const float*)d_in[2];
    const float* Wgh = (const float*)d_in[3];
    const float* Wuh = (const float*)d_in[4];
    float* out = (float*)d_out;
    unsigned short* wsw = (unsigned short*)d_ws;

    const int N = in_sizes[0] / HD;   // vt is [N,128]

    // weight prep: 217600 bf16 elements = 425 KB of d_ws
    const int prepTot = KH * GD * WPAD + KH * UD * WPAD + GD * WPAD;
    hipLaunchKernelGGL(prep_weights, dim3((prepTot + 255) / 256), dim3(256), 0, stream,
                       Wgv, Wgh, Wuh, wsw);

    hipLaunchKernelGGL(ghatt_main, dim3((N + NPB - 1) / NPB), dim3(512), 0, stream,
                       vt, H, wsw, out, N);
}